// Round 1
// baseline (174.375 us; speedup 1.0000x reference)
//
#include <hip/hip_runtime.h>
#include <hip/hip_bf16.h>

// Problem dims (AdditiveAttention_56865366999388)
#define NB 4
#define NQL 512   // query length
#define ML 512    // key/value length
#define DDIM 256  // DQ == DK == DV
#define HDIM 256  // H

static constexpr float TWO_LOG2E = 2.8853900817779268f; // 2*log2(e)
static constexpr float LOG2E     = 1.4426950408889634f;

// ---------------------------------------------------------------------------
// Kernel 1: projection.  outT[b][h][l] = TWO_LOG2E * sum_d src[b][l][d]*W[d][h]
// Stored transposed (h-major) and pre-scaled by 2*log2(e) so the scores kernel
// can do exp2(qs+ks) directly.
// grid: (l_tiles=8, h_tiles=4, z=8: z>>2 = which(0=q,1=k), z&3 = b). block 256.
// ---------------------------------------------------------------------------
__global__ __launch_bounds__(256) void proj_kernel(
    const float* __restrict__ q_src, const float* __restrict__ k_src,
    const float* __restrict__ Wq,    const float* __restrict__ Wk,
    float* __restrict__ qT,          float* __restrict__ kT)
{
    const int z = blockIdx.z;
    const int b = z & 3;
    const int which = z >> 2;
    const float* __restrict__ src  = which ? k_src : q_src;
    const float* __restrict__ W    = which ? Wk    : Wq;
    float* __restrict__       outT = which ? kT    : qT;

    const int l0 = blockIdx.x * 64;
    const int h0 = blockIdx.y * 64;
    const int t  = threadIdx.x;
    const int tx = t & 15;   // h group (4 h each)
    const int ty = t >> 4;   // l group (4 l each)

    __shared__ float sX[16][68];   // [dd][ll]
    __shared__ float sW[16][68];   // [dd][hh]

    float acc[4][4];
    #pragma unroll
    for (int i = 0; i < 4; i++)
        #pragma unroll
        for (int j = 0; j < 4; j++) acc[i][j] = 0.f;

    const int llA = t >> 2, dgA = t & 3;   // X staging: 64 l rows x 4 d-groups
    const int ddB = t >> 4, hgB = t & 15;  // W staging: 16 d rows x 16 h-groups

    for (int d0 = 0; d0 < DDIM; d0 += 16) {
        float4 xv = *(const float4*)&src[(size_t)(b * NQL + l0 + llA) * DDIM + d0 + dgA * 4];
        float4 wv = *(const float4*)&W[(size_t)(d0 + ddB) * HDIM + h0 + hgB * 4];
        __syncthreads();
        sX[dgA * 4 + 0][llA] = xv.x;
        sX[dgA * 4 + 1][llA] = xv.y;
        sX[dgA * 4 + 2][llA] = xv.z;
        sX[dgA * 4 + 3][llA] = xv.w;
        *(float4*)&sW[ddB][hgB * 4] = wv;
        __syncthreads();
        #pragma unroll
        for (int dd = 0; dd < 16; dd++) {
            float4 wr = *(const float4*)&sW[dd][tx * 4];
            float4 xr = *(const float4*)&sX[dd][ty * 4];
            float w_[4] = {wr.x, wr.y, wr.z, wr.w};
            float x_[4] = {xr.x, xr.y, xr.z, xr.w};
            #pragma unroll
            for (int i = 0; i < 4; i++)
                #pragma unroll
                for (int j = 0; j < 4; j++)
                    acc[i][j] = fmaf(w_[i], x_[j], acc[i][j]);
        }
    }

    #pragma unroll
    for (int i = 0; i < 4; i++) {
        float4 o;
        o.x = acc[i][0] * TWO_LOG2E;
        o.y = acc[i][1] * TWO_LOG2E;
        o.z = acc[i][2] * TWO_LOG2E;
        o.w = acc[i][3] * TWO_LOG2E;
        *(float4*)&outT[(size_t)(b * HDIM + h0 + tx * 4 + i) * NQL + l0 + ty * 4] = o;
    }
}

// ---------------------------------------------------------------------------
// Kernel 2: scores.  S[b][n][m] = sum_h tanh(q+k)*Wv[h]
//   = sum_h Wv[h]  -  sum_h 2*Wv[h] / (exp(2(q+k)) + 1)
// qT/kT hold 2*log2(e)*(projection), so e^{2(q+k)} = exp2(qs+ks).
// grid: (m_tiles=8, n_tiles=8, b=4). block 256; 64x64 tile; 4x4 per thread.
// ---------------------------------------------------------------------------
__global__ __launch_bounds__(256) void scores_kernel(
    const float* __restrict__ qT, const float* __restrict__ kT,
    const float* __restrict__ Wv, float* __restrict__ S)
{
    const int b  = blockIdx.z;
    const int m0 = blockIdx.x * 64;
    const int n0 = blockIdx.y * 64;
    const int t  = threadIdx.x;
    const int tx = t & 15;   // m group
    const int ty = t >> 4;   // n group

    __shared__ float sQ[32][68];   // [hh][nn]
    __shared__ float sK[32][68];   // [hh][mm]
    __shared__ float sWV[32];

    float acc[4][4];
    #pragma unroll
    for (int i = 0; i < 4; i++)
        #pragma unroll
        for (int j = 0; j < 4; j++) acc[i][j] = 0.f;
    float swv = 0.f;

    const int hhA = t >> 3, ngA = t & 7;  // staging: 32 h rows x 8 col-groups(8)

    for (int h0 = 0; h0 < HDIM; h0 += 32) {
        const float* qrow = &qT[(size_t)(b * HDIM + h0 + hhA) * NQL + n0 + ngA * 8];
        const float* krow = &kT[(size_t)(b * HDIM + h0 + hhA) * ML  + m0 + ngA * 8];
        float4 qa = ((const float4*)qrow)[0];
        float4 qb = ((const float4*)qrow)[1];
        float4 ka = ((const float4*)krow)[0];
        float4 kb = ((const float4*)krow)[1];
        float wv_ld = (t < 32) ? Wv[h0 + t] : 0.f;
        __syncthreads();
        *(float4*)&sQ[hhA][ngA * 8]     = qa;
        *(float4*)&sQ[hhA][ngA * 8 + 4] = qb;
        *(float4*)&sK[hhA][ngA * 8]     = ka;
        *(float4*)&sK[hhA][ngA * 8 + 4] = kb;
        if (t < 32) sWV[t] = wv_ld;
        __syncthreads();
        #pragma unroll 2
        for (int hh = 0; hh < 32; hh++) {
            float4 q4 = *(const float4*)&sQ[hh][ty * 4];
            float4 k4 = *(const float4*)&sK[hh][tx * 4];
            float wv = sWV[hh];
            swv += wv;
            const float nw2 = -2.0f * wv;
            float qs[4] = {q4.x, q4.y, q4.z, q4.w};
            float ks[4] = {k4.x, k4.y, k4.z, k4.w};
            #pragma unroll
            for (int i = 0; i < 4; i++)
                #pragma unroll
                for (int j = 0; j < 4; j++) {
                    float x = qs[i] + ks[j];                     // 2*log2e*(q+k)
                    float e = __builtin_amdgcn_exp2f(x);         // e^{2(q+k)}
                    float r = __builtin_amdgcn_rcpf(e + 1.0f);
                    acc[i][j] = fmaf(nw2, r, acc[i][j]);
                }
        }
    }

    #pragma unroll
    for (int i = 0; i < 4; i++) {
        float4 o;
        o.x = swv + acc[i][0];
        o.y = swv + acc[i][1];
        o.z = swv + acc[i][2];
        o.w = swv + acc[i][3];
        *(float4*)&S[(size_t)(b * NQL + n0 + ty * 4 + i) * ML + m0 + tx * 4] = o;
    }
}

// ---------------------------------------------------------------------------
// Kernel 3: row softmax over m (512) in-place. grid: 2048 rows, block 256.
// ---------------------------------------------------------------------------
__global__ __launch_bounds__(256) void softmax_kernel(float* __restrict__ S)
{
    const int row = blockIdx.x;
    float* p = &S[(size_t)row * ML];
    const int t = threadIdx.x;
    const int lane = t & 63, wid = t >> 6;

    float a = p[t];
    float c = p[t + 256];
    float mx = fmaxf(a, c);
    #pragma unroll
    for (int off = 32; off > 0; off >>= 1)
        mx = fmaxf(mx, __shfl_down(mx, off, 64));

    __shared__ float red[8];
    if (lane == 0) red[wid] = mx;
    __syncthreads();
    mx = fmaxf(fmaxf(red[0], red[1]), fmaxf(red[2], red[3]));

    float e0 = __builtin_amdgcn_exp2f((a - mx) * LOG2E);
    float e1 = __builtin_amdgcn_exp2f((c - mx) * LOG2E);
    float s = e0 + e1;
    #pragma unroll
    for (int off = 32; off > 0; off >>= 1)
        s += __shfl_down(s, off, 64);
    if (lane == 0) red[4 + wid] = s;
    __syncthreads();
    const float tot = red[4] + red[5] + red[6] + red[7];
    const float inv = 1.0f / tot;
    p[t]       = e0 * inv;
    p[t + 256] = e1 * inv;
}

// ---------------------------------------------------------------------------
// Kernel 4: out[b][n][v] = sum_m attn[b][n][m] * value[b][m][v]
// grid: (v_tiles=4, n_tiles=16, b=4). block 256; 32n x 64v tile; 2x4/thread.
// ---------------------------------------------------------------------------
__global__ __launch_bounds__(256) void av_kernel(
    const float* __restrict__ A, const float* __restrict__ V,
    float* __restrict__ O)
{
    const int b  = blockIdx.z;
    const int v0 = blockIdx.x * 64;
    const int n0 = blockIdx.y * 32;
    const int t  = threadIdx.x;
    const int tx = t & 15;   // v group (4 each)
    const int ty = t >> 4;   // n pair (2 each)

    __shared__ float sA[32][36];  // [mm][nn]
    __shared__ float sV[32][68];  // [mm][vv]

    float acc[2][4];
    #pragma unroll
    for (int i = 0; i < 2; i++)
        #pragma unroll
        for (int j = 0; j < 4; j++) acc[i][j] = 0.f;

    const int nnA = t >> 3, mgA = t & 7;  // A staging: 32 n rows x 8 m-groups(4)
    const int mmB = t >> 3, vgB = t & 7;  // V staging: 32 m rows x 8 v-groups(8)

    for (int m0 = 0; m0 < ML; m0 += 32) {
        float4 av = *(const float4*)&A[(size_t)(b * NQL + n0 + nnA) * ML + m0 + mgA * 4];
        const float* vrow = &V[(size_t)(b * ML + m0 + mmB) * DDIM + v0 + vgB * 8];
        float4 va = ((const float4*)vrow)[0];
        float4 vb = ((const float4*)vrow)[1];
        __syncthreads();
        sA[mgA * 4 + 0][nnA] = av.x;
        sA[mgA * 4 + 1][nnA] = av.y;
        sA[mgA * 4 + 2][nnA] = av.z;
        sA[mgA * 4 + 3][nnA] = av.w;
        *(float4*)&sV[mmB][vgB * 8]     = va;
        *(float4*)&sV[mmB][vgB * 8 + 4] = vb;
        __syncthreads();
        #pragma unroll 4
        for (int mm = 0; mm < 32; mm++) {
            float2 a2 = *(const float2*)&sA[mm][ty * 2];
            float4 v4 = *(const float4*)&sV[mm][tx * 4];
            acc[0][0] = fmaf(a2.x, v4.x, acc[0][0]);
            acc[0][1] = fmaf(a2.x, v4.y, acc[0][1]);
            acc[0][2] = fmaf(a2.x, v4.z, acc[0][2]);
            acc[0][3] = fmaf(a2.x, v4.w, acc[0][3]);
            acc[1][0] = fmaf(a2.y, v4.x, acc[1][0]);
            acc[1][1] = fmaf(a2.y, v4.y, acc[1][1]);
            acc[1][2] = fmaf(a2.y, v4.z, acc[1][2]);
            acc[1][3] = fmaf(a2.y, v4.w, acc[1][3]);
        }
    }

    #pragma unroll
    for (int i = 0; i < 2; i++) {
        float4 o;
        o.x = acc[i][0]; o.y = acc[i][1]; o.z = acc[i][2]; o.w = acc[i][3];
        *(float4*)&O[(size_t)(b * NQL + n0 + ty * 2 + i) * DDIM + v0 + tx * 4] = o;
    }
}

// ---------------------------------------------------------------------------
extern "C" void kernel_launch(void* const* d_in, const int* in_sizes, int n_in,
                              void* d_out, int out_size, void* d_ws, size_t ws_size,
                              hipStream_t stream)
{
    const float* query = (const float*)d_in[0]; // (4,512,256)
    const float* key   = (const float*)d_in[1]; // (4,512,256)
    const float* value = (const float*)d_in[2]; // (4,512,256)
    const float* Wq    = (const float*)d_in[3]; // (256,256)
    const float* Wk    = (const float*)d_in[4]; // (256,256)
    const float* Wv    = (const float*)d_in[5]; // (256,)
    float* out = (float*)d_out;                 // (4,512,256)

    // workspace layout (fp32): qT 2MB | kT 2MB | scores 4MB
    float* qT = (float*)d_ws;                         // [4][256][512]
    float* kT = qT + (size_t)NB * HDIM * NQL;         // [4][256][512]
    float* S  = kT + (size_t)NB * HDIM * ML;          // [4][512][512]

    dim3 gProj(NQL / 64, HDIM / 64, NB * 2);
    proj_kernel<<<gProj, 256, 0, stream>>>(query, key, Wq, Wk, qT, kT);

    dim3 gSc(ML / 64, NQL / 64, NB);
    scores_kernel<<<gSc, 256, 0, stream>>>(qT, kT, Wv, S);

    softmax_kernel<<<dim3(NB * NQL), 256, 0, stream>>>(S);

    dim3 gAv(DDIM / 64, NQL / 32, NB);
    av_kernel<<<gAv, 256, 0, stream>>>(S, value, out);
}

// Round 2
// 136.543 us; speedup vs baseline: 1.2771x; 1.2771x over previous
//
#include <hip/hip_runtime.h>
#include <hip/hip_bf16.h>

// Problem dims (AdditiveAttention_56865366999388)
#define NB 4
#define NQL 512   // query length
#define ML 512    // key/value length
#define DDIM 256  // DQ == DK == DV
#define HDIM 256  // H

static constexpr float TWO_LOG2E = 2.8853900817779268f; // 2*log2(e)
static constexpr float LOG2E     = 1.4426950408889634f;

// ---------------------------------------------------------------------------
// Kernel 1: projection + exp.
//   EqT[b][h][l] = exp2( TWO_LOG2E * sum_d q_src[b][l][d]*Wq[d][h] )  (= e^{2q})
//   EkT likewise. Stored h-major so scores kernel reads contiguous l rows.
// grid: (l_tiles=16, h_tiles=4, z=8: z>>2 which, z&3 b). block 256.
// 32l x 64h tile, 2l x 4h per thread.
// ---------------------------------------------------------------------------
__global__ __launch_bounds__(256) void proj_kernel(
    const float* __restrict__ q_src, const float* __restrict__ k_src,
    const float* __restrict__ Wq,    const float* __restrict__ Wk,
    float* __restrict__ EqT,         float* __restrict__ EkT)
{
    const int z = blockIdx.z;
    const int b = z & 3;
    const int which = z >> 2;
    const float* __restrict__ src  = which ? k_src : q_src;
    const float* __restrict__ W    = which ? Wk    : Wq;
    float* __restrict__       outT = which ? EkT   : EqT;

    const int l0 = blockIdx.x * 32;
    const int h0 = blockIdx.y * 64;
    const int t  = threadIdx.x;
    const int tx = t & 15;   // h group (4 each)
    const int ty = t >> 4;   // l (2 each)

    __shared__ float sX[32][36];   // [dd][ll]  32d x 32l
    __shared__ float sW[32][68];   // [dd][hh]  32d x 64h

    float acc[2][4];
    #pragma unroll
    for (int i = 0; i < 2; i++)
        #pragma unroll
        for (int j = 0; j < 4; j++) acc[i][j] = 0.f;

    const int llA = t >> 3, dgA = t & 7;   // X: 32 l rows x 8 d-groups(4)
    const int ddB = t >> 3, hgB = t & 7;   // W: 32 d rows x 8 h-groups(8)

    for (int d0 = 0; d0 < DDIM; d0 += 32) {
        float4 xv = *(const float4*)&src[(size_t)(b * NQL + l0 + llA) * DDIM + d0 + dgA * 4];
        const float* wrow = &W[(size_t)(d0 + ddB) * HDIM + h0 + hgB * 8];
        float4 wa = ((const float4*)wrow)[0];
        float4 wb = ((const float4*)wrow)[1];
        __syncthreads();
        sX[dgA * 4 + 0][llA] = xv.x;
        sX[dgA * 4 + 1][llA] = xv.y;
        sX[dgA * 4 + 2][llA] = xv.z;
        sX[dgA * 4 + 3][llA] = xv.w;
        *(float4*)&sW[ddB][hgB * 8]     = wa;
        *(float4*)&sW[ddB][hgB * 8 + 4] = wb;
        __syncthreads();
        #pragma unroll
        for (int dd = 0; dd < 32; dd++) {
            float4 w4 = *(const float4*)&sW[dd][tx * 4];
            float2 x2 = *(const float2*)&sX[dd][ty * 2];
            acc[0][0] = fmaf(x2.x, w4.x, acc[0][0]);
            acc[0][1] = fmaf(x2.x, w4.y, acc[0][1]);
            acc[0][2] = fmaf(x2.x, w4.z, acc[0][2]);
            acc[0][3] = fmaf(x2.x, w4.w, acc[0][3]);
            acc[1][0] = fmaf(x2.y, w4.x, acc[1][0]);
            acc[1][1] = fmaf(x2.y, w4.y, acc[1][1]);
            acc[1][2] = fmaf(x2.y, w4.z, acc[1][2]);
            acc[1][3] = fmaf(x2.y, w4.w, acc[1][3]);
        }
    }

    #pragma unroll
    for (int j = 0; j < 4; j++) {
        float2 o;
        o.x = __builtin_amdgcn_exp2f(acc[0][j] * TWO_LOG2E);
        o.y = __builtin_amdgcn_exp2f(acc[1][j] * TWO_LOG2E);
        *(float2*)&outT[(size_t)(b * HDIM + h0 + tx * 4 + j) * NQL + l0 + ty * 2] = o;
    }
}

// ---------------------------------------------------------------------------
// Kernel 2: scores.
//   tanh(q+k) = 1 - 2/(e^{2q}e^{2k}+1);  S = sum_h Wv[h] - sum_h 2*Wv[h]/a,
//   a = fma(Eq,Ek,1).  Paired reciprocal: rcp(a0*a1) then unpair via mul.
// grid: (m_tiles=16, n_tiles=16, b=4) = 1024 blocks (4/CU). block 256.
// 32x32 tile, 2n x 2m per thread.
// ---------------------------------------------------------------------------
__global__ __launch_bounds__(256) void scores_kernel(
    const float* __restrict__ EqT, const float* __restrict__ EkT,
    const float* __restrict__ Wv, float* __restrict__ S)
{
    const int b  = blockIdx.z;
    const int m0 = blockIdx.x * 32;
    const int n0 = blockIdx.y * 32;
    const int t  = threadIdx.x;
    const int tx = t & 15;   // m (2 each)
    const int ty = t >> 4;   // n (2 each)

    __shared__ float sQ[32][36];   // [hh][nn]
    __shared__ float sK[32][36];   // [hh][mm]
    __shared__ float sWV[32];

    float acc00 = 0.f, acc01 = 0.f, acc10 = 0.f, acc11 = 0.f;
    float swv = 0.f;

    const int hhA = t >> 3, cgA = t & 7;  // staging: 32 h rows x 8 col-groups(4)

    for (int h0 = 0; h0 < HDIM; h0 += 32) {
        float4 qv = *(const float4*)&EqT[(size_t)(b * HDIM + h0 + hhA) * NQL + n0 + cgA * 4];
        float4 kv = *(const float4*)&EkT[(size_t)(b * HDIM + h0 + hhA) * ML  + m0 + cgA * 4];
        float wv_ld = (t < 32) ? Wv[h0 + t] : 0.f;
        __syncthreads();
        *(float4*)&sQ[hhA][cgA * 4] = qv;
        *(float4*)&sK[hhA][cgA * 4] = kv;
        if (t < 32) sWV[t] = wv_ld;
        __syncthreads();
        #pragma unroll 8
        for (int hh = 0; hh < 32; hh++) {
            float2 q2 = *(const float2*)&sQ[hh][ty * 2];
            float2 k2 = *(const float2*)&sK[hh][tx * 2];
            float wv = sWV[hh];
            swv += wv;
            const float nw2 = -2.0f * wv;
            float a00 = fmaf(q2.x, k2.x, 1.0f);   // e^{2(q+k)} + 1
            float a01 = fmaf(q2.x, k2.y, 1.0f);
            float a10 = fmaf(q2.y, k2.x, 1.0f);
            float a11 = fmaf(q2.y, k2.y, 1.0f);
            float r0 = __builtin_amdgcn_rcpf(a00 * a01);
            float r1 = __builtin_amdgcn_rcpf(a10 * a11);
            acc00 = fmaf(nw2, r0 * a01, acc00);
            acc01 = fmaf(nw2, r0 * a00, acc01);
            acc10 = fmaf(nw2, r1 * a11, acc10);
            acc11 = fmaf(nw2, r1 * a10, acc11);
        }
    }

    float2 o0 = {swv + acc00, swv + acc01};
    float2 o1 = {swv + acc10, swv + acc11};
    *(float2*)&S[(size_t)(b * NQL + n0 + ty * 2 + 0) * ML + m0 + tx * 2] = o0;
    *(float2*)&S[(size_t)(b * NQL + n0 + ty * 2 + 1) * ML + m0 + tx * 2] = o1;
}

// ---------------------------------------------------------------------------
// Kernel 3: row softmax over m (512) in-place. grid: 2048 rows, block 256.
// ---------------------------------------------------------------------------
__global__ __launch_bounds__(256) void softmax_kernel(float* __restrict__ S)
{
    const int row = blockIdx.x;
    float* p = &S[(size_t)row * ML];
    const int t = threadIdx.x;
    const int lane = t & 63, wid = t >> 6;

    float a = p[t];
    float c = p[t + 256];
    float mx = fmaxf(a, c);
    #pragma unroll
    for (int off = 32; off > 0; off >>= 1)
        mx = fmaxf(mx, __shfl_down(mx, off, 64));

    __shared__ float red[8];
    if (lane == 0) red[wid] = mx;
    __syncthreads();
    mx = fmaxf(fmaxf(red[0], red[1]), fmaxf(red[2], red[3]));

    float e0 = __builtin_amdgcn_exp2f((a - mx) * LOG2E);
    float e1 = __builtin_amdgcn_exp2f((c - mx) * LOG2E);
    float s = e0 + e1;
    #pragma unroll
    for (int off = 32; off > 0; off >>= 1)
        s += __shfl_down(s, off, 64);
    if (lane == 0) red[4 + wid] = s;
    __syncthreads();
    const float tot = red[4] + red[5] + red[6] + red[7];
    const float inv = 1.0f / tot;
    p[t]       = e0 * inv;
    p[t + 256] = e1 * inv;
}

// ---------------------------------------------------------------------------
// Kernel 4: out[b][n][v] = sum_m attn[b][n][m] * value[b][m][v]
// grid: (v_tiles=4, n_tiles=32, b=4) = 512 blocks. block 256.
// 16n x 64v tile, 1n x 4v per thread.
// ---------------------------------------------------------------------------
__global__ __launch_bounds__(256) void av_kernel(
    const float* __restrict__ A, const float* __restrict__ V,
    float* __restrict__ O)
{
    const int b  = blockIdx.z;
    const int v0 = blockIdx.x * 64;
    const int n0 = blockIdx.y * 16;
    const int t  = threadIdx.x;
    const int tx = t & 15;   // v group (4 each)
    const int ty = t >> 4;   // n (1 each)

    __shared__ float sA[32][20];  // [mm][nn] 32m x 16n
    __shared__ float sV[32][68];  // [mm][vv] 32m x 64v

    float4 acc = {0.f, 0.f, 0.f, 0.f};

    const int nnA = t >> 4, mgA = t & 15;  // A: 16 n rows x 16 m-groups(2)
    const int mmB = t >> 3, vgB = t & 7;   // V: 32 m rows x 8 v-groups(8)

    for (int m0 = 0; m0 < ML; m0 += 32) {
        float2 av = *(const float2*)&A[(size_t)(b * NQL + n0 + nnA) * ML + m0 + mgA * 2];
        const float* vrow = &V[(size_t)(b * ML + m0 + mmB) * DDIM + v0 + vgB * 8];
        float4 va = ((const float4*)vrow)[0];
        float4 vb = ((const float4*)vrow)[1];
        __syncthreads();
        sA[mgA * 2 + 0][nnA] = av.x;
        sA[mgA * 2 + 1][nnA] = av.y;
        *(float4*)&sV[mmB][vgB * 8]     = va;
        *(float4*)&sV[mmB][vgB * 8 + 4] = vb;
        __syncthreads();
        #pragma unroll
        for (int mm = 0; mm < 32; mm++) {
            float a = sA[mm][ty];
            float4 v4 = *(const float4*)&sV[mm][tx * 4];
            acc.x = fmaf(a, v4.x, acc.x);
            acc.y = fmaf(a, v4.y, acc.y);
            acc.z = fmaf(a, v4.z, acc.z);
            acc.w = fmaf(a, v4.w, acc.w);
        }
    }

    *(float4*)&O[(size_t)(b * NQL + n0 + ty) * DDIM + v0 + tx * 4] = acc;
}

// ---------------------------------------------------------------------------
extern "C" void kernel_launch(void* const* d_in, const int* in_sizes, int n_in,
                              void* d_out, int out_size, void* d_ws, size_t ws_size,
                              hipStream_t stream)
{
    const float* query = (const float*)d_in[0]; // (4,512,256)
    const float* key   = (const float*)d_in[1]; // (4,512,256)
    const float* value = (const float*)d_in[2]; // (4,512,256)
    const float* Wq    = (const float*)d_in[3]; // (256,256)
    const float* Wk    = (const float*)d_in[4]; // (256,256)
    const float* Wv    = (const float*)d_in[5]; // (256,)
    float* out = (float*)d_out;                 // (4,512,256)

    // workspace layout (fp32): EqT 2MB | EkT 2MB | scores 4MB
    float* EqT = (float*)d_ws;                        // [4][256][512]
    float* EkT = EqT + (size_t)NB * HDIM * NQL;       // [4][256][512]
    float* S   = EkT + (size_t)NB * HDIM * ML;        // [4][512][512]

    dim3 gProj(NQL / 32, HDIM / 64, NB * 2);
    proj_kernel<<<gProj, 256, 0, stream>>>(query, key, Wq, Wk, EqT, EkT);

    dim3 gSc(ML / 32, NQL / 32, NB);
    scores_kernel<<<gSc, 256, 0, stream>>>(EqT, EkT, Wv, S);

    softmax_kernel<<<dim3(NB * NQL), 256, 0, stream>>>(S);

    dim3 gAv(DDIM / 64, NQL / 16, NB);
    av_kernel<<<gAv, 256, 0, stream>>>(S, value, out);
}